// Round 1
// baseline (98.699 us; speedup 1.0000x reference)
//
#include <hip/hip_runtime.h>
#include <hip/hip_fp16.h>

#define NTYPES 3
#define FDIM 64
#define HDIM 64
#define OUTD 64
#define D1C 100

// One wave (64 lanes) per target node; lane j = output channel j.
// LDS: W fp32 (3*64*64*4 = 48KB) + Wout fp16 (128*64*2 = 16KB) = 64KB exactly.
__global__ __launch_bounds__(512, 2)
void shgnn_kernel(const float* __restrict__ f0,
                  const float* __restrict__ f1,
                  const float* __restrict__ f2,
                  const float* __restrict__ W,
                  const float* __restrict__ b,
                  const float* __restrict__ Wc,
                  const float* __restrict__ bc,
                  const float* __restrict__ Wout,
                  const float* __restrict__ bout,
                  const int* __restrict__ type_mask,
                  const int* __restrict__ deg1,
                  const int* __restrict__ deg2,
                  const int* __restrict__ tgt,
                  int T, int per_type,
                  float* __restrict__ out_logits,
                  float* __restrict__ out_h)
{
    __shared__ float  sW[NTYPES * FDIM * HDIM];   // 48 KB
    __shared__ __half sWout[2 * HDIM * OUTD];     // 16 KB

    const int tid = threadIdx.x;

    // ---- stage weights ----
    {
        const float4* src = reinterpret_cast<const float4*>(W);
        float4* dst = reinterpret_cast<float4*>(sW);
        for (int i = tid; i < NTYPES * FDIM * HDIM / 4; i += 512)
            dst[i] = src[i];
        for (int i = tid; i < 2 * HDIM * OUTD; i += 512)
            sWout[i] = __float2half(Wout[i]);
    }
    __syncthreads();

    const int lane = tid & 63;
    const int wid  = tid >> 6;

    // per-lane biases (b/bc fp32; bout quantized to fp16 as in reference)
    const float b_l0  = b[0 * HDIM + lane];
    const float b_l1  = b[1 * HDIM + lane];
    const float b_l2  = b[2 * HDIM + lane];
    const float bc_l0 = bc[0 * HDIM + lane];
    const float bc_l1 = bc[1 * HDIM + lane];
    const float bc_l2 = bc[2 * HDIM + lane];
    const float bout_l = __half2float(__float2half(bout[lane]));

    const int gw = blockIdx.x * 8 + wid;     // global wave id
    const int gstride = gridDim.x * 8;

    for (int t = gw; t < T; t += gstride) {
        const int n  = tgt[t];
        const int ty = type_mask[n];                 // 0..2, wave-uniform
        const int p  = n - ty * per_type;

        const float* f = (ty == 0 ? f0 : (ty == 1 ? f1 : f2)) + (size_t)p * FDIM;
        const float fv = f[lane];                    // coalesced 256B row gather

        // ---- h1 = leaky(f @ W[ty] + b[ty]) ----
        float acc = (ty == 0 ? b_l0 : (ty == 1 ? b_l1 : b_l2));
        const float* w = sW + ty * (FDIM * HDIM);
        #pragma unroll
        for (int k = 0; k < FDIM; ++k) {
            const float fk = __uint_as_float(
                __builtin_amdgcn_readlane(__float_as_uint(fv), k));
            acc = fmaf(fk, w[k * HDIM + lane], acc);
        }
        acc = (acc >= 0.f) ? acc : 0.7f * acc;

        // ---- h2 = leaky(Wc[ty][d1] + Wc[ty][100+d2] + bc[ty]) ----
        const int d1i = deg1[n];
        const int d2i = deg2[n];
        const float* wc = Wc + (size_t)ty * (200 * HDIM);
        float acc2 = (ty == 0 ? bc_l0 : (ty == 1 ? bc_l1 : bc_l2))
                   + wc[d1i * HDIM + lane]
                   + wc[(D1C + d2i) * HDIM + lane];
        acc2 = (acc2 >= 0.f) ? acc2 : 0.7f * acc2;

        // x = concat(h1,h2) cast to fp16 (reference: astype(float16))
        const float x1 = __half2float(__float2half(acc));
        const float x2 = __half2float(__float2half(acc2));

        // ---- logits = x @ Wout_fp16 + bout_fp16 ----
        float lg = bout_l;
        #pragma unroll
        for (int k = 0; k < HDIM; ++k) {
            const float xk = __uint_as_float(
                __builtin_amdgcn_readlane(__float_as_uint(x1), k));
            lg = fmaf(xk, __half2float(sWout[k * OUTD + lane]), lg);
        }
        #pragma unroll
        for (int k = 0; k < HDIM; ++k) {
            const float xk = __uint_as_float(
                __builtin_amdgcn_readlane(__float_as_uint(x2), k));
            lg = fmaf(xk, __half2float(sWout[(HDIM + k) * OUTD + lane]), lg);
        }
        lg = __half2float(__float2half(lg));         // output is fp16 in reference

        // ---- stores (coalesced 256B per wave) ----
        out_logits[(size_t)t * OUTD + lane] = lg;
        out_h[(size_t)t * (2 * HDIM) + lane]        = x1;
        out_h[(size_t)t * (2 * HDIM) + HDIM + lane] = x2;
    }
}

extern "C" void kernel_launch(void* const* d_in, const int* in_sizes, int n_in,
                              void* d_out, int out_size, void* d_ws, size_t ws_size,
                              hipStream_t stream) {
    const float* f0   = (const float*)d_in[0];
    const float* f1   = (const float*)d_in[1];
    const float* f2   = (const float*)d_in[2];
    const float* W    = (const float*)d_in[3];
    const float* b    = (const float*)d_in[4];
    const float* Wc   = (const float*)d_in[5];
    const float* bc   = (const float*)d_in[6];
    const float* Wout = (const float*)d_in[7];
    const float* bout = (const float*)d_in[8];
    const int* type_mask = (const int*)d_in[9];
    const int* deg1   = (const int*)d_in[10];
    const int* deg2   = (const int*)d_in[11];
    const int* tgt    = (const int*)d_in[12];

    const int T = in_sizes[12];
    const int per_type = in_sizes[0] / FDIM;

    float* out_logits = (float*)d_out;
    float* out_h = out_logits + (size_t)T * OUTD;

    int blocks = (T + 7) / 8;          // 8 waves per block
    if (blocks > 512) blocks = 512;    // 2 blocks/CU resident (64KB LDS each)

    shgnn_kernel<<<dim3(blocks), dim3(512), 0, stream>>>(
        f0, f1, f2, W, b, Wc, bc, Wout, bout,
        type_mask, deg1, deg2, tgt, T, per_type,
        out_logits, out_h);
}

// Round 2
// 73.889 us; speedup vs baseline: 1.3358x; 1.3358x over previous
//
#include <hip/hip_runtime.h>
#include <hip/hip_fp16.h>

#define NTYPES 3
#define FDIM 64
#define HDIM 64
#define OUTD 64
#define GSZ 13           // targets per wave-group (3*ceil(T/GSZ) <= 4096 waves for T=50000)

// ---------------- pass 1: bucket target indices by node type ----------------
__global__ void bucket_kernel(const int* __restrict__ tgt, int T, int per_type,
                              int* __restrict__ counters, int* __restrict__ lists, int cap)
{
    __shared__ int scnt[NTYPES];
    __shared__ int sbase[NTYPES];
    const int tid = threadIdx.x;
    if (tid < NTYPES) scnt[tid] = 0;
    __syncthreads();
    const int t = blockIdx.x * blockDim.x + tid;
    int ty = 0, pos = 0;
    if (t < T) {
        const int n = tgt[t];
        ty = (n >= 2 * per_type) ? 2 : (n >= per_type ? 1 : 0);
        pos = atomicAdd(&scnt[ty], 1);
    }
    __syncthreads();
    if (tid < NTYPES) sbase[tid] = atomicAdd(&counters[tid], scnt[tid]);
    __syncthreads();
    if (t < T) lists[ty * cap + sbase[ty] + pos] = t;
}

// ---------------- pass 2: type-uniform groups of GSZ targets per wave -------
__global__ __launch_bounds__(512, 2)
void shgnn_main(const float* __restrict__ f0,
                const float* __restrict__ f1,
                const float* __restrict__ f2,
                const float* __restrict__ W,
                const float* __restrict__ b,
                const float* __restrict__ Wc,
                const float* __restrict__ bc,
                const float* __restrict__ Wout,
                const float* __restrict__ bout,
                const int* __restrict__ tgt,
                const int* __restrict__ deg1,
                const int* __restrict__ deg2,
                const int* __restrict__ counters,
                const int* __restrict__ lists, int cap,
                int per_type,
                float* __restrict__ out_logits,
                float* __restrict__ out_h)
{
    __shared__ float  sW[NTYPES * FDIM * HDIM];   // 48 KB fp32
    __shared__ __half2 sWout2[HDIM * OUTD];       // 16 KB: [k2][j] = (Wout[2k2][j], Wout[2k2+1][j])

    const int tid = threadIdx.x;

    {
        const float4* src = reinterpret_cast<const float4*>(W);
        float4* dst = reinterpret_cast<float4*>(sW);
        for (int i = tid; i < NTYPES * FDIM * HDIM / 4; i += 512)
            dst[i] = src[i];
        for (int i = tid; i < HDIM * OUTD; i += 512) {
            const int k2 = i >> 6, j = i & 63;
            sWout2[i] = __floats2half2_rn(Wout[(2 * k2) * OUTD + j],
                                          Wout[(2 * k2 + 1) * OUTD + j]);
        }
    }
    __syncthreads();

    const int lane = tid & 63;
    const int wave = __builtin_amdgcn_readfirstlane(blockIdx.x * 8 + (tid >> 6));
    const int nwaves = gridDim.x * 8;

    const int c0 = counters[0], c1 = counters[1], c2 = counters[2];
    const int g0 = (c0 + GSZ - 1) / GSZ;
    const int g1 = (c1 + GSZ - 1) / GSZ;
    const int g2 = (c2 + GSZ - 1) / GSZ;
    const int ng = g0 + g1 + g2;

    // per-lane biases
    const float b_l0  = b[0 * HDIM + lane];
    const float b_l1  = b[1 * HDIM + lane];
    const float b_l2  = b[2 * HDIM + lane];
    const float bc_l0 = bc[0 * HDIM + lane];
    const float bc_l1 = bc[1 * HDIM + lane];
    const float bc_l2 = bc[2 * HDIM + lane];
    const float bout_l = __half2float(__float2half(bout[lane]));

    for (int g = wave; g < ng; g += nwaves) {
        int ty, gi, cnt;
        if (g < g0)           { ty = 0; gi = g;            cnt = c0; }
        else if (g < g0 + g1) { ty = 1; gi = g - g0;       cnt = c1; }
        else                  { ty = 2; gi = g - g0 - g1;  cnt = c2; }
        const int base = gi * GSZ;
        const int m = (cnt - base < GSZ) ? (cnt - base) : GSZ;
        const int* list = lists + ty * cap;

        int t[GSZ], nn[GSZ], d1i[GSZ], d2i[GSZ];
        #pragma unroll
        for (int i = 0; i < GSZ; ++i) t[i] = list[base + (i < m ? i : 0)];
        #pragma unroll
        for (int i = 0; i < GSZ; ++i) nn[i] = tgt[t[i]];
        #pragma unroll
        for (int i = 0; i < GSZ; ++i) { d1i[i] = deg1[nn[i]]; d2i[i] = deg2[nn[i]]; }

        const float* fb = (ty == 0 ? f0 : (ty == 1 ? f1 : f2));
        float fv[GSZ];
        #pragma unroll
        for (int i = 0; i < GSZ; ++i)
            fv[i] = fb[(size_t)(nn[i] - ty * per_type) * FDIM + lane];

        // ---- h1 = leaky(f @ W[ty] + b[ty]); one LDS read shared by GSZ targets ----
        const float blt = (ty == 0 ? b_l0 : (ty == 1 ? b_l1 : b_l2));
        const float* w = sW + ty * (FDIM * HDIM);
        float acc[GSZ];
        #pragma unroll
        for (int i = 0; i < GSZ; ++i) acc[i] = blt;
        #pragma unroll 4
        for (int k = 0; k < FDIM; ++k) {
            const float wk = w[k * HDIM + lane];
            #pragma unroll
            for (int i = 0; i < GSZ; ++i) {
                const float fk = __uint_as_float(
                    __builtin_amdgcn_readlane(__float_as_uint(fv[i]), k));
                acc[i] = fmaf(fk, wk, acc[i]);
            }
        }
        float x1[GSZ];
        #pragma unroll
        for (int i = 0; i < GSZ; ++i) {
            float a = acc[i];
            a = (a >= 0.f) ? a : 0.7f * a;
            x1[i] = __half2float(__float2half(a));
        }

        // ---- h2 = leaky(Wc[ty][d1] + Wc[ty][100+d2] + bc[ty]) ----
        const float bclt = (ty == 0 ? bc_l0 : (ty == 1 ? bc_l1 : bc_l2));
        const float* wc = Wc + (size_t)ty * (200 * HDIM);
        float x2[GSZ];
        #pragma unroll
        for (int i = 0; i < GSZ; ++i) {
            float a = bclt + wc[d1i[i] * HDIM + lane] + wc[(100 + d2i[i]) * HDIM + lane];
            a = (a >= 0.f) ? a : 0.7f * a;
            x2[i] = __half2float(__float2half(a));
        }

        // ---- logits = [x1,x2] @ Wout_fp16 + bout_fp16 (fp32 accum) ----
        float lg[GSZ];
        #pragma unroll
        for (int i = 0; i < GSZ; ++i) lg[i] = bout_l;
        #pragma unroll 2
        for (int k2 = 0; k2 < 32; ++k2) {
            const __half2 wv = sWout2[k2 * OUTD + lane];
            const float wlo = __half2float(__low2half(wv));
            const float whi = __half2float(__high2half(wv));
            #pragma unroll
            for (int i = 0; i < GSZ; ++i) {
                const float xa = __uint_as_float(
                    __builtin_amdgcn_readlane(__float_as_uint(x1[i]), 2 * k2));
                const float xb = __uint_as_float(
                    __builtin_amdgcn_readlane(__float_as_uint(x1[i]), 2 * k2 + 1));
                lg[i] = fmaf(xa, wlo, fmaf(xb, whi, lg[i]));
            }
        }
        #pragma unroll 2
        for (int k2 = 32; k2 < 64; ++k2) {
            const __half2 wv = sWout2[k2 * OUTD + lane];
            const float wlo = __half2float(__low2half(wv));
            const float whi = __half2float(__high2half(wv));
            #pragma unroll
            for (int i = 0; i < GSZ; ++i) {
                const float xa = __uint_as_float(
                    __builtin_amdgcn_readlane(__float_as_uint(x2[i]), 2 * k2 - 64));
                const float xb = __uint_as_float(
                    __builtin_amdgcn_readlane(__float_as_uint(x2[i]), 2 * k2 - 63));
                lg[i] = fmaf(xa, wlo, fmaf(xb, whi, lg[i]));
            }
        }

        // ---- stores ----
        #pragma unroll
        for (int i = 0; i < GSZ; ++i) {
            const float o = __half2float(__float2half(lg[i]));
            out_logits[(size_t)t[i] * OUTD + lane] = o;
            out_h[(size_t)t[i] * (2 * HDIM) + lane]        = x1[i];
            out_h[(size_t)t[i] * (2 * HDIM) + HDIM + lane] = x2[i];
        }
    }
}

// ---------------- fallback (R1 kernel) if ws too small ----------------------
__global__ __launch_bounds__(512, 2)
void shgnn_fallback(const float* __restrict__ f0, const float* __restrict__ f1,
                    const float* __restrict__ f2, const float* __restrict__ W,
                    const float* __restrict__ b, const float* __restrict__ Wc,
                    const float* __restrict__ bc, const float* __restrict__ Wout,
                    const float* __restrict__ bout, const int* __restrict__ type_mask,
                    const int* __restrict__ deg1, const int* __restrict__ deg2,
                    const int* __restrict__ tgt, int T, int per_type,
                    float* __restrict__ out_logits, float* __restrict__ out_h)
{
    __shared__ float  sW[NTYPES * FDIM * HDIM];
    __shared__ __half sWout[2 * HDIM * OUTD];
    const int tid = threadIdx.x;
    {
        const float4* src = reinterpret_cast<const float4*>(W);
        float4* dst = reinterpret_cast<float4*>(sW);
        for (int i = tid; i < NTYPES * FDIM * HDIM / 4; i += 512) dst[i] = src[i];
        for (int i = tid; i < 2 * HDIM * OUTD; i += 512) sWout[i] = __float2half(Wout[i]);
    }
    __syncthreads();
    const int lane = tid & 63;
    const int wid  = tid >> 6;
    const float b_l0 = b[lane], b_l1 = b[HDIM + lane], b_l2 = b[2 * HDIM + lane];
    const float bc_l0 = bc[lane], bc_l1 = bc[HDIM + lane], bc_l2 = bc[2 * HDIM + lane];
    const float bout_l = __half2float(__float2half(bout[lane]));
    const int gw = blockIdx.x * 8 + wid;
    const int gstride = gridDim.x * 8;
    for (int t = gw; t < T; t += gstride) {
        const int n  = tgt[t];
        const int ty = type_mask[n];
        const int p  = n - ty * per_type;
        const float* f = (ty == 0 ? f0 : (ty == 1 ? f1 : f2)) + (size_t)p * FDIM;
        const float fv = f[lane];
        float acc = (ty == 0 ? b_l0 : (ty == 1 ? b_l1 : b_l2));
        const float* w = sW + ty * (FDIM * HDIM);
        #pragma unroll
        for (int k = 0; k < FDIM; ++k) {
            const float fk = __uint_as_float(
                __builtin_amdgcn_readlane(__float_as_uint(fv), k));
            acc = fmaf(fk, w[k * HDIM + lane], acc);
        }
        acc = (acc >= 0.f) ? acc : 0.7f * acc;
        const int d1 = deg1[n], d2 = deg2[n];
        const float* wc = Wc + (size_t)ty * (200 * HDIM);
        float acc2 = (ty == 0 ? bc_l0 : (ty == 1 ? bc_l1 : bc_l2))
                   + wc[d1 * HDIM + lane] + wc[(100 + d2) * HDIM + lane];
        acc2 = (acc2 >= 0.f) ? acc2 : 0.7f * acc2;
        const float x1 = __half2float(__float2half(acc));
        const float x2 = __half2float(__float2half(acc2));
        float lg = bout_l;
        #pragma unroll
        for (int k = 0; k < HDIM; ++k) {
            const float xk = __uint_as_float(
                __builtin_amdgcn_readlane(__float_as_uint(x1), k));
            lg = fmaf(xk, __half2float(sWout[k * OUTD + lane]), lg);
        }
        #pragma unroll
        for (int k = 0; k < HDIM; ++k) {
            const float xk = __uint_as_float(
                __builtin_amdgcn_readlane(__float_as_uint(x2), k));
            lg = fmaf(xk, __half2float(sWout[(HDIM + k) * OUTD + lane]), lg);
        }
        lg = __half2float(__float2half(lg));
        out_logits[(size_t)t * OUTD + lane] = lg;
        out_h[(size_t)t * (2 * HDIM) + lane]        = x1;
        out_h[(size_t)t * (2 * HDIM) + HDIM + lane] = x2;
    }
}

extern "C" void kernel_launch(void* const* d_in, const int* in_sizes, int n_in,
                              void* d_out, int out_size, void* d_ws, size_t ws_size,
                              hipStream_t stream) {
    const float* f0   = (const float*)d_in[0];
    const float* f1   = (const float*)d_in[1];
    const float* f2   = (const float*)d_in[2];
    const float* W    = (const float*)d_in[3];
    const float* b    = (const float*)d_in[4];
    const float* Wc   = (const float*)d_in[5];
    const float* bc   = (const float*)d_in[6];
    const float* Wout = (const float*)d_in[7];
    const float* bout = (const float*)d_in[8];
    const int* type_mask = (const int*)d_in[9];
    const int* deg1   = (const int*)d_in[10];
    const int* deg2   = (const int*)d_in[11];
    const int* tgt    = (const int*)d_in[12];

    const int T = in_sizes[12];
    const int per_type = in_sizes[0] / FDIM;

    float* out_logits = (float*)d_out;
    float* out_h = out_logits + (size_t)T * OUTD;

    const size_t ws_needed = (size_t)(16 + 3 * (size_t)T) * sizeof(int);
    if (ws_size >= ws_needed) {
        int* counters = (int*)d_ws;
        int* lists    = counters + 16;
        hipMemsetAsync(counters, 0, 16 * sizeof(int), stream);
        bucket_kernel<<<dim3((T + 255) / 256), dim3(256), 0, stream>>>(
            tgt, T, per_type, counters, lists, T);
        shgnn_main<<<dim3(512), dim3(512), 0, stream>>>(
            f0, f1, f2, W, b, Wc, bc, Wout, bout,
            tgt, deg1, deg2, counters, lists, T, per_type,
            out_logits, out_h);
    } else {
        int blocks = (T + 7) / 8;
        if (blocks > 512) blocks = 512;
        shgnn_fallback<<<dim3(blocks), dim3(512), 0, stream>>>(
            f0, f1, f2, W, b, Wc, bc, Wout, bout,
            type_mask, deg1, deg2, tgt, T, per_type,
            out_logits, out_h);
    }
}

// Round 4
// 44.501 us; speedup vs baseline: 2.2179x; 1.6604x over previous
//
#include <hip/hip_runtime.h>
#include <hip/hip_fp16.h>

#define NTYPES 3

typedef _Float16 half8 __attribute__((ext_vector_type(8)));
typedef _Float16 half4v __attribute__((ext_vector_type(4)));
typedef float f32x4 __attribute__((ext_vector_type(4)));

// ---------------- pass 1: bucket target indices by node type ----------------
__global__ void bucket_kernel(const int* __restrict__ tgt, int T, int per_type,
                              int* __restrict__ counters, int* __restrict__ lists, int cap)
{
    __shared__ int scnt[NTYPES];
    __shared__ int sbase[NTYPES];
    const int tid = threadIdx.x;
    if (tid < NTYPES) scnt[tid] = 0;
    __syncthreads();
    const int t = blockIdx.x * blockDim.x + tid;
    int ty = 0, pos = 0;
    if (t < T) {
        const int n = tgt[t];
        ty = (n >= 2 * per_type) ? 2 : (n >= per_type ? 1 : 0);
        pos = atomicAdd(&scnt[ty], 1);
    }
    __syncthreads();
    if (tid < NTYPES) sbase[tid] = atomicAdd(&counters[tid], scnt[tid]);
    __syncthreads();
    if (t < T) lists[ty * cap + sbase[ty] + pos] = t;
}

__device__ __forceinline__ float leakyf(float v) { return v >= 0.f ? v : 0.7f * v; }

// ---------------- pass 2: MFMA over type-uniform tiles of 16 targets --------
// Wave-private X buffer in LDS converts MFMA C/D layout -> next A layout.
// All weight panels fp16 in LDS, transposed [n][k], XOR-swizzled (T2).
__global__ __launch_bounds__(256, 2)
void shgnn_mfma(const float* __restrict__ f0, const float* __restrict__ f1,
                const float* __restrict__ f2, const float* __restrict__ W,
                const float* __restrict__ b, const float* __restrict__ Wc,
                const float* __restrict__ bc, const float* __restrict__ Wout,
                const float* __restrict__ bout,
                const int* __restrict__ tgt, const int* __restrict__ deg1,
                const int* __restrict__ deg2,
                const int* __restrict__ counters, const int* __restrict__ lists,
                int cap, int per_type,
                float* __restrict__ out_logits, float* __restrict__ out_h)
{
    __shared__ _Float16 sWT[3 * 4096];   // 24KB: [ty][n=64][k=64] swizzled
    __shared__ _Float16 sWoutT[8192];    // 16KB: [col=64][k=128] swizzled
    __shared__ _Float16 sX[4 * 2048];    // 16KB: per-wave [row=16][ch=128] swizzled

    char* const sWTb = (char*)sWT;
    char* const sWoutTb = (char*)sWoutT;

    const int tid = threadIdx.x;

    // stage W^T (fp32 -> fp16), coalesced reads, swizzled LDS writes
    for (int e = tid; e < 3 * 4096; e += 256) {
        const int ty = e >> 12, r = e & 4095, k = r >> 6, n = r & 63;
        const int off = (ty * 8192 + n * 128 + k * 2) ^ ((n & 7) << 4);
        *(_Float16*)(sWTb + off) = (_Float16)W[ty * 4096 + k * 64 + n];
    }
    // stage Wout^T
    for (int e = tid; e < 8192; e += 256) {
        const int k = e >> 6, n = e & 63;
        const int off = (n * 256 + k * 2) ^ ((n & 7) << 4);
        *(_Float16*)(sWoutTb + off) = (_Float16)Wout[k * 64 + n];
    }
    __syncthreads();

    const int lane = tid & 63;
    const int l15 = lane & 15;
    const int lq  = lane >> 4;                       // quad 0..3
    char* const sXw = (char*)sX + (tid >> 6) * 4096; // wave-private 4KB

    const int c0 = counters[0], c1 = counters[1], c2 = counters[2];
    const int g0 = (c0 + 15) >> 4, g1v = (c1 + 15) >> 4, g2v = (c2 + 15) >> 4;
    const int ng = g0 + g1v + g2v;

    float boutv[4];
    #pragma unroll
    for (int n = 0; n < 4; ++n)
        boutv[n] = (float)(_Float16)bout[n * 16 + l15];

    const int gwave = blockIdx.x * 4 + (tid >> 6);
    const int nwaves = gridDim.x * 4;

    for (int g = gwave; g < ng; g += nwaves) {
        int ty, gi, cnt;
        if (g < g0)            { ty = 0; gi = g;             cnt = c0; }
        else if (g < g0 + g1v) { ty = 1; gi = g - g0;        cnt = c1; }
        else                   { ty = 2; gi = g - g0 - g1v;  cnt = c2; }
        const int base = gi << 4;
        const int m = (cnt - base < 16) ? (cnt - base) : 16;

        // lane i (mod 16) owns target row i of the tile (padded rows dup row 0)
        const int idx = base + (l15 < m ? l15 : 0);
        const int tvv = lists[ty * cap + idx];
        const int nnv = tgt[tvv];
        const int d1v = deg1[nnv];
        const int d2v = deg2[nnv];

        float bn[4];
        #pragma unroll
        for (int n = 0; n < 4; ++n) bn[n] = b[ty * 64 + n * 16 + l15];

        // ---- A fragments: row l15, k = lq*8.. (fp32 -> fp16, RNE) ----
        const float* fbase = (ty == 0 ? f0 : (ty == 1 ? f1 : f2));
        const float* frp = fbase + (size_t)(nnv - ty * per_type) * 64 + (lq << 3);
        const f32x4 a00 = *(const f32x4*)frp;
        const f32x4 a01 = *(const f32x4*)(frp + 4);
        const f32x4 a10 = *(const f32x4*)(frp + 32);
        const f32x4 a11 = *(const f32x4*)(frp + 36);
        const half8 a0 = {(_Float16)a00.x, (_Float16)a00.y, (_Float16)a00.z, (_Float16)a00.w,
                          (_Float16)a01.x, (_Float16)a01.y, (_Float16)a01.z, (_Float16)a01.w};
        const half8 a1 = {(_Float16)a10.x, (_Float16)a10.y, (_Float16)a10.z, (_Float16)a10.w,
                          (_Float16)a11.x, (_Float16)a11.y, (_Float16)a11.z, (_Float16)a11.w};

        const int sw = (lane & 7) << 4;

        // ---- h1 = leaky(F @ W[ty] + b[ty]) : 8 MFMA, write X[.., 0..63] ----
        #pragma unroll
        for (int n = 0; n < 4; ++n) {
            const int colb = ty * 8192 + (n * 16 + l15) * 128 + (lq << 4);
            const half8 wb0 = *(const half8*)__builtin_assume_aligned((sWTb + (colb ^ sw)), 16);
            const half8 wb1 = *(const half8*)__builtin_assume_aligned((sWTb + ((colb + 64) ^ sw)), 16);
            f32x4 acc = {bn[n], bn[n], bn[n], bn[n]};
            acc = __builtin_amdgcn_mfma_f32_16x16x32_f16(a0, wb0, acc, 0, 0, 0);
            acc = __builtin_amdgcn_mfma_f32_16x16x32_f16(a1, wb1, acc, 0, 0, 0);
            #pragma unroll
            for (int r = 0; r < 4; ++r) {
                const int row = (lq << 2) + r;               // C/D: row=(lane>>4)*4+reg
                const float v = leakyf(acc[r]);
                const int off = (row * 256 + (n * 16 + l15) * 2) ^ ((row & 7) << 4);
                *(_Float16*)(sXw + off) = (_Float16)v;       // RNE, matches astype(f16)
            }
        }

        // ---- h2 = leaky(Wc[ty][d1] + Wc[ty][100+d2] + bc[ty]) -> X[.., 64..127] ----
        {
            const int cb = lq << 4;                          // 16 ch per lane
            const float* wcb = Wc + (size_t)ty * 12800;
            const float* q1 = wcb + (size_t)d1v * 64 + cb;
            const float* q2 = wcb + (size_t)(100 + d2v) * 64 + cb;
            const float* qb = bc + ty * 64 + cb;
            #pragma unroll
            for (int q = 0; q < 4; ++q) {
                const f32x4 u  = *(const f32x4*)(q1 + q * 4);
                const f32x4 w2 = *(const f32x4*)(q2 + q * 4);
                const f32x4 bb = *(const f32x4*)(qb + q * 4);
                half4v hv;
                #pragma unroll
                for (int j = 0; j < 4; ++j)
                    hv[j] = (_Float16)leakyf(u[j] + w2[j] + bb[j]);
                const int off = (l15 * 256 + 128 + cb * 2 + q * 8) ^ ((l15 & 7) << 4);
                *(half4v*)__builtin_assume_aligned((sXw + off), 8) = hv;
            }
        }

        // ---- logits = X @ Wout + bout : 16 MFMA ----
        half8 xa[4];
        #pragma unroll
        for (int ks = 0; ks < 4; ++ks) {
            const int off = (l15 * 256 + ks * 64 + (lq << 4)) ^ ((l15 & 7) << 4);
            xa[ks] = *(const half8*)__builtin_assume_aligned((sXw + off), 16);
        }
        int tr[4];
        #pragma unroll
        for (int r = 0; r < 4; ++r) tr[r] = __shfl(tvv, (lq << 2) + r);

        #pragma unroll
        for (int n = 0; n < 4; ++n) {
            f32x4 acc = {boutv[n], boutv[n], boutv[n], boutv[n]};
            const int colb = (n * 16 + l15) * 256 + (lq << 4);
            #pragma unroll
            for (int ks = 0; ks < 4; ++ks) {
                const half8 wf = *(const half8*)__builtin_assume_aligned(
                    (sWoutTb + ((colb + ks * 64) ^ sw)), 16);
                acc = __builtin_amdgcn_mfma_f32_16x16x32_f16(xa[ks], wf, acc, 0, 0, 0);
            }
            #pragma unroll
            for (int r = 0; r < 4; ++r) {
                const float v = (float)(_Float16)acc[r];     // final fp16 round
                out_logits[(size_t)tr[r] * 64 + n * 16 + l15] = v;
            }
        }

        // ---- out_h: coalesced fp32 store from X ----
        {
            const int rh = lane >> 2;
            const int tb = __shfl(tvv, rh);
            const int cb2 = (lane & 3) << 5;                 // 32 halves per lane
            float* op = out_h + (size_t)tb * 128 + cb2;
            #pragma unroll
            for (int p = 0; p < 4; ++p) {
                const int off = (rh * 256 + cb2 * 2 + p * 16) ^ ((rh & 7) << 4);
                const half8 hv = *(const half8*)__builtin_assume_aligned((sXw + off), 16);
                f32x4 o0 = {(float)hv[0], (float)hv[1], (float)hv[2], (float)hv[3]};
                f32x4 o1 = {(float)hv[4], (float)hv[5], (float)hv[6], (float)hv[7]};
                *(f32x4*)(op + p * 8) = o0;
                *(f32x4*)(op + p * 8 + 4) = o1;
            }
        }
    }
}

// ---------------- fallback (R1 kernel) if ws too small ----------------------
__global__ __launch_bounds__(512, 2)
void shgnn_fallback(const float* __restrict__ f0, const float* __restrict__ f1,
                    const float* __restrict__ f2, const float* __restrict__ W,
                    const float* __restrict__ b, const float* __restrict__ Wc,
                    const float* __restrict__ bc, const float* __restrict__ Wout,
                    const float* __restrict__ bout, const int* __restrict__ type_mask,
                    const int* __restrict__ deg1, const int* __restrict__ deg2,
                    const int* __restrict__ tgt, int T, int per_type,
                    float* __restrict__ out_logits, float* __restrict__ out_h)
{
    __shared__ float  sW[NTYPES * 64 * 64];
    __shared__ __half sWout[2 * 64 * 64];
    const int tid = threadIdx.x;
    {
        const float4* src = reinterpret_cast<const float4*>(W);
        float4* dst = reinterpret_cast<float4*>(sW);
        for (int i = tid; i < NTYPES * 64 * 64 / 4; i += 512) dst[i] = src[i];
        for (int i = tid; i < 2 * 64 * 64; i += 512) sWout[i] = __float2half(Wout[i]);
    }
    __syncthreads();
    const int lane = tid & 63;
    const int wid  = tid >> 6;
    const float b_l0 = b[lane], b_l1 = b[64 + lane], b_l2 = b[128 + lane];
    const float bc_l0 = bc[lane], bc_l1 = bc[64 + lane], bc_l2 = bc[128 + lane];
    const float bout_l = __half2float(__float2half(bout[lane]));
    const int gw = blockIdx.x * 8 + wid;
    const int gstride = gridDim.x * 8;
    for (int t = gw; t < T; t += gstride) {
        const int n  = tgt[t];
        const int ty = type_mask[n];
        const int p  = n - ty * per_type;
        const float* f = (ty == 0 ? f0 : (ty == 1 ? f1 : f2)) + (size_t)p * 64;
        const float fv = f[lane];
        float acc = (ty == 0 ? b_l0 : (ty == 1 ? b_l1 : b_l2));
        const float* w = sW + ty * 4096;
        #pragma unroll
        for (int k = 0; k < 64; ++k) {
            const float fk = __uint_as_float(
                __builtin_amdgcn_readlane(__float_as_uint(fv), k));
            acc = fmaf(fk, w[k * 64 + lane], acc);
        }
        acc = (acc >= 0.f) ? acc : 0.7f * acc;
        const int d1 = deg1[n], d2 = deg2[n];
        const float* wc = Wc + (size_t)ty * 12800;
        float acc2 = (ty == 0 ? bc_l0 : (ty == 1 ? bc_l1 : bc_l2))
                   + wc[d1 * 64 + lane] + wc[(100 + d2) * 64 + lane];
        acc2 = (acc2 >= 0.f) ? acc2 : 0.7f * acc2;
        const float x1 = __half2float(__float2half(acc));
        const float x2 = __half2float(__float2half(acc2));
        float lg = bout_l;
        #pragma unroll
        for (int k = 0; k < 64; ++k) {
            const float xk = __uint_as_float(
                __builtin_amdgcn_readlane(__float_as_uint(x1), k));
            lg = fmaf(xk, __half2float(sWout[k * 64 + lane]), lg);
        }
        #pragma unroll
        for (int k = 0; k < 64; ++k) {
            const float xk = __uint_as_float(
                __builtin_amdgcn_readlane(__float_as_uint(x2), k));
            lg = fmaf(xk, __half2float(sWout[(64 + k) * 64 + lane]), lg);
        }
        lg = __half2float(__float2half(lg));
        out_logits[(size_t)t * 64 + lane] = lg;
        out_h[(size_t)t * 128 + lane]      = x1;
        out_h[(size_t)t * 128 + 64 + lane] = x2;
    }
}

extern "C" void kernel_launch(void* const* d_in, const int* in_sizes, int n_in,
                              void* d_out, int out_size, void* d_ws, size_t ws_size,
                              hipStream_t stream) {
    const float* f0   = (const float*)d_in[0];
    const float* f1   = (const float*)d_in[1];
    const float* f2   = (const float*)d_in[2];
    const float* W    = (const float*)d_in[3];
    const float* b    = (const float*)d_in[4];
    const float* Wc   = (const float*)d_in[5];
    const float* bc   = (const float*)d_in[6];
    const float* Wout = (const float*)d_in[7];
    const float* bout = (const float*)d_in[8];
    const int* type_mask = (const int*)d_in[9];
    const int* deg1   = (const int*)d_in[10];
    const int* deg2   = (const int*)d_in[11];
    const int* tgt    = (const int*)d_in[12];

    const int T = in_sizes[12];
    const int per_type = in_sizes[0] / 64;

    float* out_logits = (float*)d_out;
    float* out_h = out_logits + (size_t)T * 64;

    const size_t ws_needed = (size_t)(16 + 3 * (size_t)T) * sizeof(int);
    if (ws_size >= ws_needed) {
        int* counters = (int*)d_ws;
        int* lists    = counters + 16;
        (void)hipMemsetAsync(counters, 0, 16 * sizeof(int), stream);
        bucket_kernel<<<dim3((T + 255) / 256), dim3(256), 0, stream>>>(
            tgt, T, per_type, counters, lists, T);
        shgnn_mfma<<<dim3(1024), dim3(256), 0, stream>>>(
            f0, f1, f2, W, b, Wc, bc, Wout, bout,
            tgt, deg1, deg2, counters, lists, T, per_type,
            out_logits, out_h);
    } else {
        int blocks = (T + 7) / 8;
        if (blocks > 512) blocks = 512;
        shgnn_fallback<<<dim3(blocks), dim3(512), 0, stream>>>(
            f0, f1, f2, W, b, Wc, bc, Wout, bout,
            type_mask, deg1, deg2, tgt, T, per_type,
            out_logits, out_h);
    }
}

// Round 5
// 33.441 us; speedup vs baseline: 2.9515x; 1.3307x over previous
//
#include <hip/hip_runtime.h>
#include <hip/hip_fp16.h>

typedef _Float16 half8 __attribute__((ext_vector_type(8)));
typedef _Float16 half4v __attribute__((ext_vector_type(4)));
typedef float f32x4 __attribute__((ext_vector_type(4)));

__device__ __forceinline__ float leakyf(float v) { return v >= 0.f ? v : 0.7f * v; }

// ---------------- prep: build MFMA B-fragment blobs in ws (fp16) ------------
// Stacked-W B: [K=192][64] (K = 3 types * 64). 24 frags (ks 0..5, n 0..3).
// Wout B: [K=128][64]. 16 frags (ks 0..3, n 0..3).
// Frag element (lane, j) = B[ks*32 + (lane>>4)*8 + j][n*16 + (lane&15)].
// Blob layout: frag*512 + lane*8 + j  -> one dwordx4 per lane, coalesced.
__global__ void prep_kernel(const float* __restrict__ W, const float* __restrict__ Wout,
                            _Float16* __restrict__ wsW, _Float16* __restrict__ wsO)
{
    const int tid = threadIdx.x + blockIdx.x * blockDim.x;
    const int stride = blockDim.x * gridDim.x;
    for (int e = tid; e < 24 * 512; e += stride) {
        const int frag = e >> 9, r = e & 511;
        const int lane = r >> 3, j = r & 7;
        const int ks = frag >> 2, n = frag & 3;
        const int k = ks * 32 + ((lane >> 4) << 3) + j;    // 0..191
        const int col = n * 16 + (lane & 15);
        const int ty = k >> 6, kk = k & 63;
        wsW[e] = (_Float16)W[ty * 4096 + kk * 64 + col];
    }
    for (int e = tid; e < 16 * 512; e += stride) {
        const int frag = e >> 9, r = e & 511;
        const int lane = r >> 3, j = r & 7;
        const int ks = frag >> 2, n = frag & 3;
        const int k = ks * 32 + ((lane >> 4) << 3) + j;    // 0..127
        const int col = n * 16 + (lane & 15);
        wsO[e] = (_Float16)Wout[k * 64 + col];
    }
}

// ---------------- main: one wave per 16-target tile, mixed types ------------
// h1 via K=192 zero-padded MFMA (type selects the live 64-k band).
// Wave-private swizzled X buffer in LDS converts C/D layout -> next A layout.
__global__ __launch_bounds__(256, 4)
void shgnn_mfma2(const float* __restrict__ f0, const float* __restrict__ f1,
                 const float* __restrict__ f2,
                 const float* __restrict__ b, const float* __restrict__ Wc,
                 const float* __restrict__ bc, const float* __restrict__ bout,
                 const int* __restrict__ tgt, const int* __restrict__ deg1,
                 const int* __restrict__ deg2,
                 const _Float16* __restrict__ wsW, const _Float16* __restrict__ wsO,
                 int T, int per_type,
                 float* __restrict__ out_logits, float* __restrict__ out_h)
{
    __shared__ _Float16 sX[4][2048];     // 16KB: per-wave [row=16][ch=128] swizzled
    __shared__ float sB[192];
    __shared__ float sBC[192];
    __shared__ float sBout[64];

    const int tid = threadIdx.x;
    if (tid < 192) sB[tid] = b[tid];
    if (tid < 192) sBC[tid] = bc[tid];
    if (tid < 64)  sBout[tid] = bout[tid];
    __syncthreads();

    const int ntiles = (T + 15) >> 4;
    const int tile = blockIdx.x * 4 + (tid >> 6);
    if (tile >= ntiles) return;

    const int lane = tid & 63;
    const int l15 = lane & 15;
    const int lq  = lane >> 4;
    char* const sXw = (char*)sX[tid >> 6];

    // lane (mod 16) owns tile row l15
    int t = tile * 16 + l15;
    if (t >= T) t = T - 1;                       // duplicate rows write same value
    const int nnv = tgt[t];                      // coalesced 64B per wave
    const int tyv = (nnv >= 2 * per_type) ? 2 : (nnv >= per_type ? 1 : 0);
    const int d1v = deg1[nnv];
    const int d2v = deg2[nnv];

    // ---- A fragments from f-row (fp32 -> fp16 RNE) ----
    const float* fb = (tyv == 0) ? f0 : ((tyv == 1) ? f1 : f2);
    const float* frp = fb + (size_t)(nnv - tyv * per_type) * 64 + (lq << 3);
    const f32x4 a00 = *(const f32x4*)frp;
    const f32x4 a01 = *(const f32x4*)(frp + 4);
    const f32x4 a10 = *(const f32x4*)(frp + 32);
    const f32x4 a11 = *(const f32x4*)(frp + 36);
    const half8 a0 = {(_Float16)a00.x, (_Float16)a00.y, (_Float16)a00.z, (_Float16)a00.w,
                      (_Float16)a01.x, (_Float16)a01.y, (_Float16)a01.z, (_Float16)a01.w};
    const half8 a1 = {(_Float16)a10.x, (_Float16)a10.y, (_Float16)a10.z, (_Float16)a10.w,
                      (_Float16)a11.x, (_Float16)a11.y, (_Float16)a11.z, (_Float16)a11.w};
    const half8 z8 = {(_Float16)0.f, (_Float16)0.f, (_Float16)0.f, (_Float16)0.f,
                      (_Float16)0.f, (_Float16)0.f, (_Float16)0.f, (_Float16)0.f};
    const int k0 = 2 * tyv, k1 = 2 * tyv + 1;    // live k-slices in stacked K

    // per-row types for bias lookup (rows 0..15 held by lanes 0..15)
    int tyr[4];
    #pragma unroll
    for (int r = 0; r < 4; ++r) tyr[r] = __shfl(tyv, (lq << 2) + r);

    // ---- h1 = leaky(F~ @ Wstacked + b[ty_row]) : 24 MFMA, write X[.., 0..63] ----
    #pragma unroll
    for (int n = 0; n < 4; ++n) {
        f32x4 acc = {0.f, 0.f, 0.f, 0.f};
        #pragma unroll
        for (int ks = 0; ks < 6; ++ks) {
            const half8 av = (ks == k0) ? a0 : ((ks == k1) ? a1 : z8);
            const half8 wb = *(const half8*)__builtin_assume_aligned(
                (wsW + (ks * 4 + n) * 512 + lane * 8), 16);
            acc = __builtin_amdgcn_mfma_f32_16x16x32_f16(av, wb, acc, 0, 0, 0);
        }
        #pragma unroll
        for (int r = 0; r < 4; ++r) {
            const int row = (lq << 2) + r;               // C/D: row=(lane>>4)*4+reg
            const float v = leakyf(acc[r] + sB[tyr[r] * 64 + n * 16 + l15]);
            const int off = (row * 256 + (n * 16 + l15) * 2) ^ ((row & 7) << 4);
            *(_Float16*)(sXw + off) = (_Float16)v;       // RNE, matches astype(f16)
        }
    }

    // ---- h2 = leaky(Wc[ty][d1] + Wc[ty][100+d2] + bc[ty]) -> X[.., 64..127] ----
    {
        const int cb = lq << 4;                          // 16 ch per lane
        const float* wcb = Wc + (size_t)tyv * 12800;
        const float* q1 = wcb + (size_t)d1v * 64 + cb;
        const float* q2 = wcb + (size_t)(100 + d2v) * 64 + cb;
        const float* qb = &sBC[tyv * 64 + cb];
        #pragma unroll
        for (int q = 0; q < 4; ++q) {
            const f32x4 u  = *(const f32x4*)(q1 + q * 4);
            const f32x4 w2 = *(const f32x4*)(q2 + q * 4);
            const f32x4 bb = *(const f32x4*)(qb + q * 4);
            half4v hv;
            #pragma unroll
            for (int j = 0; j < 4; ++j)
                hv[j] = (_Float16)leakyf(u[j] + w2[j] + bb[j]);
            const int off = (l15 * 256 + 128 + cb * 2 + q * 8) ^ ((l15 & 7) << 4);
            *(half4v*)__builtin_assume_aligned((sXw + off), 8) = hv;
        }
    }

    // ---- logits = X @ Wout + bout : 16 MFMA ----
    half8 xa[4];
    #pragma unroll
    for (int ks = 0; ks < 4; ++ks) {
        const int off = (l15 * 256 + ks * 64 + (lq << 4)) ^ ((l15 & 7) << 4);
        xa[ks] = *(const half8*)__builtin_assume_aligned((sXw + off), 16);
    }
    #pragma unroll
    for (int n = 0; n < 4; ++n) {
        const float bo = (float)(_Float16)sBout[n * 16 + l15];
        f32x4 acc = {bo, bo, bo, bo};
        #pragma unroll
        for (int ks = 0; ks < 4; ++ks) {
            const half8 wf = *(const half8*)__builtin_assume_aligned(
                (wsO + (ks * 4 + n) * 512 + lane * 8), 16);
            acc = __builtin_amdgcn_mfma_f32_16x16x32_f16(xa[ks], wf, acc, 0, 0, 0);
        }
        #pragma unroll
        for (int r = 0; r < 4; ++r) {
            int trr = tile * 16 + (lq << 2) + r;
            if (trr >= T) trr = T - 1;                   // duplicate row, same value
            out_logits[(size_t)trr * 64 + n * 16 + l15] = (float)(_Float16)acc[r];
        }
    }

    // ---- out_h: coalesced fp32 store from X ----
    {
        const int rh = lane >> 2;
        int tb = tile * 16 + rh;
        if (tb >= T) tb = T - 1;
        const int cb2 = (lane & 3) << 5;                 // 32 halves per lane
        float* op = out_h + (size_t)tb * 128 + cb2;
        #pragma unroll
        for (int p = 0; p < 4; ++p) {
            const int off = (rh * 256 + cb2 * 2 + p * 16) ^ ((rh & 7) << 4);
            const half8 hv = *(const half8*)__builtin_assume_aligned((sXw + off), 16);
            f32x4 o0 = {(float)hv[0], (float)hv[1], (float)hv[2], (float)hv[3]};
            f32x4 o1 = {(float)hv[4], (float)hv[5], (float)hv[6], (float)hv[7]};
            *(f32x4*)(op + p * 8) = o0;
            *(f32x4*)(op + p * 8 + 4) = o1;
        }
    }
}

// ---------------- fallback (R1 kernel) if ws too small ----------------------
__global__ __launch_bounds__(512, 2)
void shgnn_fallback(const float* __restrict__ f0, const float* __restrict__ f1,
                    const float* __restrict__ f2, const float* __restrict__ W,
                    const float* __restrict__ b, const float* __restrict__ Wc,
                    const float* __restrict__ bc, const float* __restrict__ Wout,
                    const float* __restrict__ bout, const int* __restrict__ type_mask,
                    const int* __restrict__ deg1, const int* __restrict__ deg2,
                    const int* __restrict__ tgt, int T, int per_type,
                    float* __restrict__ out_logits, float* __restrict__ out_h)
{
    __shared__ float  sW[3 * 64 * 64];
    __shared__ __half sWout[2 * 64 * 64];
    const int tid = threadIdx.x;
    {
        const float4* src = reinterpret_cast<const float4*>(W);
        float4* dst = reinterpret_cast<float4*>(sW);
        for (int i = tid; i < 3 * 64 * 64 / 4; i += 512) dst[i] = src[i];
        for (int i = tid; i < 2 * 64 * 64; i += 512) sWout[i] = __float2half(Wout[i]);
    }
    __syncthreads();
    const int lane = tid & 63;
    const int wid  = tid >> 6;
    const float b_l0 = b[lane], b_l1 = b[64 + lane], b_l2 = b[128 + lane];
    const float bc_l0 = bc[lane], bc_l1 = bc[64 + lane], bc_l2 = bc[128 + lane];
    const float bout_l = __half2float(__float2half(bout[lane]));
    const int gw = blockIdx.x * 8 + wid;
    const int gstride = gridDim.x * 8;
    for (int t = gw; t < T; t += gstride) {
        const int n  = tgt[t];
        const int ty = type_mask[n];
        const int p  = n - ty * per_type;
        const float* f = (ty == 0 ? f0 : (ty == 1 ? f1 : f2)) + (size_t)p * 64;
        const float fv = f[lane];
        float acc = (ty == 0 ? b_l0 : (ty == 1 ? b_l1 : b_l2));
        const float* w = sW + ty * 4096;
        #pragma unroll
        for (int k = 0; k < 64; ++k) {
            const float fk = __uint_as_float(
                __builtin_amdgcn_readlane(__float_as_uint(fv), k));
            acc = fmaf(fk, w[k * 64 + lane], acc);
        }
        acc = (acc >= 0.f) ? acc : 0.7f * acc;
        const int d1 = deg1[n], d2 = deg2[n];
        const float* wc = Wc + (size_t)ty * 12800;
        float acc2 = (ty == 0 ? bc_l0 : (ty == 1 ? bc_l1 : bc_l2))
                   + wc[d1 * 64 + lane] + wc[(100 + d2) * 64 + lane];
        acc2 = (acc2 >= 0.f) ? acc2 : 0.7f * acc2;
        const float x1 = __half2float(__float2half(acc));
        const float x2 = __half2float(__float2half(acc2));
        float lg = bout_l;
        #pragma unroll
        for (int k = 0; k < 64; ++k) {
            const float xk = __uint_as_float(
                __builtin_amdgcn_readlane(__float_as_uint(x1), k));
            lg = fmaf(xk, __half2float(sWout[k * 64 + lane]), lg);
        }
        #pragma unroll
        for (int k = 0; k < 64; ++k) {
            const float xk = __uint_as_float(
                __builtin_amdgcn_readlane(__float_as_uint(x2), k));
            lg = fmaf(xk, __half2float(sWout[(64 + k) * 64 + lane]), lg);
        }
        lg = __half2float(__float2half(lg));
        out_logits[(size_t)t * 64 + lane] = lg;
        out_h[(size_t)t * 128 + lane]      = x1;
        out_h[(size_t)t * 128 + 64 + lane] = x2;
    }
}

extern "C" void kernel_launch(void* const* d_in, const int* in_sizes, int n_in,
                              void* d_out, int out_size, void* d_ws, size_t ws_size,
                              hipStream_t stream) {
    const float* f0   = (const float*)d_in[0];
    const float* f1   = (const float*)d_in[1];
    const float* f2   = (const float*)d_in[2];
    const float* W    = (const float*)d_in[3];
    const float* b    = (const float*)d_in[4];
    const float* Wc   = (const float*)d_in[5];
    const float* bc   = (const float*)d_in[6];
    const float* Wout = (const float*)d_in[7];
    const float* bout = (const float*)d_in[8];
    const int* type_mask = (const int*)d_in[9];
    const int* deg1   = (const int*)d_in[10];
    const int* deg2   = (const int*)d_in[11];
    const int* tgt    = (const int*)d_in[12];

    const int T = in_sizes[12];
    const int per_type = in_sizes[0] / 64;

    float* out_logits = (float*)d_out;
    float* out_h = out_logits + (size_t)T * 64;

    const size_t ws_needed = (size_t)(24 * 512 + 16 * 512) * sizeof(_Float16);
    if (ws_size >= ws_needed) {
        _Float16* wsW = (_Float16*)d_ws;
        _Float16* wsO = wsW + 24 * 512;
        prep_kernel<<<dim3(20), dim3(256), 0, stream>>>(W, Wout, wsW, wsO);
        const int ntiles = (T + 15) / 16;
        const int blocks = (ntiles + 3) / 4;
        shgnn_mfma2<<<dim3(blocks), dim3(256), 0, stream>>>(
            f0, f1, f2, b, Wc, bc, bout, tgt, deg1, deg2,
            wsW, wsO, T, per_type, out_logits, out_h);
    } else {
        int blocks = (T + 7) / 8;
        if (blocks > 512) blocks = 512;
        shgnn_fallback<<<dim3(blocks), dim3(512), 0, stream>>>(
            f0, f1, f2, W, b, Wc, bc, Wout, bout,
            type_mask, deg1, deg2, tgt, T, per_type,
            out_logits, out_h);
    }
}